// Round 1
// baseline (734.144 us; speedup 1.0000x reference)
//
#include <hip/hip_runtime.h>
#include <math.h>

#define H 512
#define NH 4
#define D 128
#define B 2
#define S 256
#define BS (B*S)   // 512
#define PI_F 3.14159265358979323846f
#define INV_SQRT_D 0.08838834764831845f  // 1/sqrt(128)

// ------------------------------------------------------------------
// Generic tiled fp32 GEMM: C[M,N] = act(A[M,K] @ W[K,N] + bias[N])
// 64x64 tile, BK=16, 256 threads, 4x4 micro-tile per thread.
// Requires M%64==0, N%64==0, K%16==0 (all our shapes satisfy this).
// ACT: 0 = none, 1 = sigmoid(x)*PI, 2 = sigmoid(x)
// ------------------------------------------------------------------
template<int ACT>
__global__ __launch_bounds__(256)
void gemm_bias_act(const float* __restrict__ A, int lda,
                   const float* __restrict__ Bw, int ldb,
                   const float* __restrict__ bias,
                   float* __restrict__ C, int ldc, int K)
{
    __shared__ float As[64][17];   // [m][k], pad to 17 to break bank conflicts
    __shared__ float Bs[16][64];   // [k][n]
    const int tid = threadIdx.x;
    const int tr = tid >> 4, tc = tid & 15;
    const int bm = blockIdx.y, bn = blockIdx.x;
    float acc[4][4] = {};
    const int am = tid >> 2;            // 0..63
    const int ak = (tid & 3) << 2;      // 0,4,8,12
    const int bnn = tid & 63;           // 0..63
    const int bk0 = tid >> 6;           // 0..3

    for (int k0 = 0; k0 < K; k0 += 16) {
        const float* Ap = A + (bm*64 + am)*lda + k0 + ak;
        As[am][ak+0] = Ap[0];
        As[am][ak+1] = Ap[1];
        As[am][ak+2] = Ap[2];
        As[am][ak+3] = Ap[3];
        #pragma unroll
        for (int l = 0; l < 4; ++l) {
            int k = bk0 + l*4;
            Bs[k][bnn] = Bw[(size_t)(k0 + k)*ldb + bn*64 + bnn];
        }
        __syncthreads();
        #pragma unroll
        for (int kk = 0; kk < 16; ++kk) {
            float a[4], bb[4];
            #pragma unroll
            for (int i = 0; i < 4; ++i) a[i] = As[tr*4+i][kk];
            #pragma unroll
            for (int j = 0; j < 4; ++j) bb[j] = Bs[kk][tc*4+j];
            #pragma unroll
            for (int i = 0; i < 4; ++i)
                #pragma unroll
                for (int j = 0; j < 4; ++j)
                    acc[i][j] = fmaf(a[i], bb[j], acc[i][j]);
        }
        __syncthreads();
    }
    #pragma unroll
    for (int i = 0; i < 4; ++i) {
        int row = bm*64 + tr*4 + i;
        #pragma unroll
        for (int j = 0; j < 4; ++j) {
            int col = bn*64 + tc*4 + j;
            float v = acc[i][j] + bias[col];
            if (ACT == 1)      v = PI_F / (1.f + __expf(-v));
            else if (ACT == 2) v = 1.f  / (1.f + __expf(-v));
            C[(size_t)row*ldc + col] = v;
        }
    }
}

// ------------------------------------------------------------------
// Wave attention. Key insight: amp/omega/ph depend only on the query
// position i (not j), and |score| <= 1/sqrt(D) so softmax needs no
// max-subtraction. One thread per (b,i,c) output channel.
// ------------------------------------------------------------------
__global__ __launch_bounds__(512)
void attn_kernel(const float* __restrict__ omega,
                 const float* __restrict__ amp,
                 const float* __restrict__ vmat,
                 float* __restrict__ ctx)
{
    const int bi = blockIdx.x;          // b*S + i
    const int b = bi >> 8;
    const int i = bi & 255;
    const int c = threadIdx.x;          // 0..511 (channel = h*D+d)
    const int rowq = bi*H + c;
    const float om = omega[rowq];
    const float am = amp[rowq] * INV_SQRT_D;
    const float ph = tanhf(vmat[rowq]) * PI_F;
    float se = 0.f, sev = 0.f;
    const float* vb = vmat + (size_t)b*S*H + c;
    for (int j = 0; j < S; ++j) {
        float ang = fmaf(om, (float)(i - j), ph);
        float sc = am * __cosf(ang);
        float e = __expf(sc);
        se += e;
        sev = fmaf(e, vb[(size_t)j*H], sev);
    }
    ctx[rowq] = sev / se;
}

// ------------------------------------------------------------------
// Combine the 3 centered convs (k=3/p=1, k=5/p=2, k=9/p=4) into one
// 9-tap weight in im2col layout: Wbig[(t*H+i)*H + o]
// ------------------------------------------------------------------
__device__ __forceinline__ void softmax3(const float* sw, float& w0, float& w1, float& w2)
{
    float s0 = sw[0], s1 = sw[1], s2 = sw[2];
    float mx = fmaxf(s0, fmaxf(s1, s2));
    float e0 = __expf(s0-mx), e1 = __expf(s1-mx), e2 = __expf(s2-mx);
    float inv = 1.f/(e0+e1+e2);
    w0 = e0*inv; w1 = e1*inv; w2 = e2*inv;
}

__global__ void prep_wbig(const float* __restrict__ cw1, const float* __restrict__ cw2,
                          const float* __restrict__ cw3, const float* __restrict__ scale_w,
                          float* __restrict__ Wbig)
{
    int idx = blockIdx.x*256 + threadIdx.x;   // < 9*H*H
    float w0, w1, w2; softmax3(scale_w, w0, w1, w2);
    int t = idx / (H*H);
    int rem = idx - t*(H*H);
    int i = rem >> 9;       // /H
    int o = rem & 511;      // %H
    float v = w2 * cw3[((size_t)o*H + i)*9 + t];
    if (t >= 3 && t < 6) v = fmaf(w0, cw1[((size_t)o*H+i)*3 + (t-3)], v);
    if (t >= 2 && t < 7) v = fmaf(w1, cw2[((size_t)o*H+i)*5 + (t-2)], v);
    Wbig[(size_t)(t*H + i)*H + o] = v;
}

__global__ void prep_beff(const float* __restrict__ cb1, const float* __restrict__ cb2,
                          const float* __restrict__ cb3, const float* __restrict__ scale_w,
                          float* __restrict__ beff)
{
    int c = threadIdx.x;
    float w0, w1, w2; softmax3(scale_w, w0, w1, w2);
    beff[c] = w0*cb1[c] + w1*cb2[c] + w2*cb3[c];
}

// im2col for the 9-tap conv: Abig[r][t*H+i] = x[b, s+t-4, i] (0 outside)
__global__ void gather_abig(const float* __restrict__ x, float* __restrict__ Abig)
{
    int idx = blockIdx.x*256 + threadIdx.x;   // < BS*4608
    int r = idx / 4608;
    int col = idx - r*4608;
    int t = col >> 9;
    int i = col & 511;
    int b = r >> 8;
    int s = r & 255;
    int s2 = s + t - 4;
    float v = (s2 >= 0 && s2 < S) ? x[((size_t)b*S + s2)*H + i] : 0.f;
    Abig[idx] = v;
}

// ------------------------------------------------------------------
// Phase branch step 1: p, mag, and per-(b,c) means of cos(p)/sin(p) over S
// ------------------------------------------------------------------
__global__ __launch_bounds__(256)
void phase_stats(const float* __restrict__ cr, float* __restrict__ pbuf,
                 float* __restrict__ magbuf, float* __restrict__ mc, float* __restrict__ ms)
{
    int bc = blockIdx.x;        // b*H + c
    int b = bc >> 9;
    int c = bc & 511;
    int s = threadIdx.x;        // 0..255 == S
    const float* row = cr + ((size_t)b*S + s)*(2*H);
    float re = row[c], im = row[c + H];
    float p = atan2f(im, re);
    float mag = sqrtf(fmaf(re, re, fmaf(im, im, 1e-5f)));
    pbuf[((size_t)b*S+s)*H + c] = p;
    magbuf[((size_t)b*S+s)*H + c] = mag;
    __shared__ float sc[256], ss[256];
    sc[s] = cosf(p); ss[s] = sinf(p);
    __syncthreads();
    for (int off = 128; off > 0; off >>= 1) {
        if (s < off) { sc[s] += sc[s+off]; ss[s] += ss[s+off]; }
        __syncthreads();
    }
    if (s == 0) { mc[bc] = sc[0]*(1.f/S); ms[bc] = ss[0]*(1.f/S); }
}

// Phase branch step 2: mix + rebuild complex components (nc, BSx2H)
__global__ void phase_mix(const float* __restrict__ pbuf, const float* __restrict__ magbuf,
                          const float* __restrict__ phase_shifts,
                          const float* __restrict__ mc, const float* __restrict__ ms,
                          float* __restrict__ nc)
{
    int idx = blockIdx.x*256 + threadIdx.x;  // < BS*H
    int r = idx >> 9;
    int c = idx & 511;
    int b = r >> 8;
    float p = pbuf[idx], mag = magbuf[idx];
    float psh = phase_shifts[c];
    float mixed = cosf(p+psh)*mc[b*H+c] + sinf(p+psh)*ms[b*H+c];
    float np_ = fmaf(0.1f, mixed, p);
    float sn, cn;
    sincosf(np_, &sn, &cn);
    nc[(size_t)r*(2*H) + c]     = mag*cn;
    nc[(size_t)r*(2*H) + c + H] = mag*sn;
}

// ------------------------------------------------------------------
// Residual + LayerNorm -> d_out
// ------------------------------------------------------------------
__global__ __launch_bounds__(256)
void final_ln(const float* __restrict__ x, const float* __restrict__ comb,
              const float* __restrict__ g, const float* __restrict__ bta,
              float* __restrict__ out)
{
    int r = blockIdx.x;      // 0..BS-1
    int t = threadIdx.x;     // 0..255, each handles c=t and c=t+256
    const float* xr = x + (size_t)r*H;
    const float* cb = comb + (size_t)r*H;
    float v0 = xr[t] + cb[t];
    float v1 = xr[t+256] + cb[t+256];
    __shared__ float red[256];
    red[t] = v0 + v1;
    __syncthreads();
    for (int off = 128; off > 0; off >>= 1) {
        if (t < off) red[t] += red[t+off];
        __syncthreads();
    }
    float mu = red[0] * (1.f/H);
    __syncthreads();
    float d0 = v0 - mu, d1 = v1 - mu;
    red[t] = d0*d0 + d1*d1;
    __syncthreads();
    for (int off = 128; off > 0; off >>= 1) {
        if (t < off) red[t] += red[t+off];
        __syncthreads();
    }
    float inv = rsqrtf(red[0]*(1.f/H) + 1e-5f);
    out[(size_t)r*H + t]       = d0*inv*g[t]     + bta[t];
    out[(size_t)r*H + t + 256] = d1*inv*g[t+256] + bta[t+256];
}

// ------------------------------------------------------------------
extern "C" void kernel_launch(void* const* d_in, const int* in_sizes, int n_in,
                              void* d_out, int out_size, void* d_ws, size_t ws_size,
                              hipStream_t stream)
{
    const float* x   = (const float*)d_in[0];
    const float* Wq  = (const float*)d_in[1];
    const float* bq  = (const float*)d_in[2];
    const float* Wk  = (const float*)d_in[3];
    const float* bk  = (const float*)d_in[4];
    const float* Wv  = (const float*)d_in[5];
    const float* bv  = (const float*)d_in[6];
    const float* Wo  = (const float*)d_in[7];
    const float* bo  = (const float*)d_in[8];
    const float* cw1 = (const float*)d_in[9];
    const float* cb1 = (const float*)d_in[10];
    const float* cw2 = (const float*)d_in[11];
    const float* cb2 = (const float*)d_in[12];
    const float* cw3 = (const float*)d_in[13];
    const float* cb3 = (const float*)d_in[14];
    const float* scale_w = (const float*)d_in[15];
    const float* Wwl = (const float*)d_in[16];
    const float* bwl = (const float*)d_in[17];
    const float* Wtc = (const float*)d_in[18];
    const float* btc = (const float*)d_in[19];
    const float* Wfc = (const float*)d_in[20];
    const float* bfc = (const float*)d_in[21];
    const float* phase_shifts = (const float*)d_in[22];
    const float* Wproj = (const float*)d_in[23];
    const float* bproj = (const float*)d_in[24];
    const float* ln_g = (const float*)d_in[25];
    const float* ln_b = (const float*)d_in[26];
    float* out = (float*)d_out;

    // workspace layout (floats)
    float* ws = (float*)d_ws;
    float* omega   = ws;                   // BS*H
    float* amp     = omega   + BS*H;       // BS*H
    float* vmat    = amp     + BS*H;       // BS*H
    float* ctx     = vmat    + BS*H;       // BS*H
    float* cr      = ctx     + BS*H;       // BS*2H
    float* pbuf    = cr      + BS*2*H;     // BS*H
    float* magbuf  = pbuf    + BS*H;       // BS*H
    float* nc      = magbuf  + BS*H;       // BS*2H
    float* mc      = nc      + BS*2*H;     // B*H
    float* ms      = mc      + B*H;        // B*H
    float* beff    = ms      + B*H;        // H
    float* Wbig    = beff    + H;          // 9*H*H (im2col weight, K-major)
    float* Abig    = Wbig    + 9*H*H;      // BS*9*H (im2col input)
    float* convout = Abig    + (size_t)BS*9*H; // BS*H
    float* concat  = convout + BS*H;       // BS*3H  [wave|wavelet|phase]
    float* combined= concat  + BS*3*H;     // BS*H

    const dim3 blk(256);
    const dim3 g88(8, 8), g168(16, 8);

    // wavelet prep
    prep_wbig <<<9*H*H/256, blk, 0, stream>>>(cw1, cw2, cw3, scale_w, Wbig);
    prep_beff <<<1, H, 0, stream>>>(cb1, cb2, cb3, scale_w, beff);
    gather_abig<<<BS*9*H/256, blk, 0, stream>>>(x, Abig);

    // projections
    gemm_bias_act<1><<<g88, blk, 0, stream>>>(x, H, Wq, H, bq, omega, H, H);   // omega = sigmoid(q)*PI
    gemm_bias_act<2><<<g88, blk, 0, stream>>>(x, H, Wk, H, bk, amp,   H, H);   // amp = sigmoid(k)
    gemm_bias_act<0><<<g88, blk, 0, stream>>>(x, H, Wv, H, bv, vmat,  H, H);   // v (ph derived later)
    gemm_bias_act<0><<<g168, blk, 0, stream>>>(x, H, Wtc, 2*H, btc, cr, 2*H, H); // complex rep

    // wavelet branch: 9-tap conv as one GEMM, then @Wwl -> concat[:,512:1024]
    gemm_bias_act<0><<<g88, blk, 0, stream>>>(Abig, 9*H, Wbig, H, beff, convout, H, 9*H);
    gemm_bias_act<0><<<g88, blk, 0, stream>>>(convout, H, Wwl, H, bwl, concat + H, 3*H, H);

    // wave attention branch -> concat[:,0:512]
    attn_kernel<<<BS, H, 0, stream>>>(omega, amp, vmat, ctx);
    gemm_bias_act<0><<<g88, blk, 0, stream>>>(ctx, H, Wo, H, bo, concat, 3*H, H);

    // phase branch -> concat[:,1024:1536]
    phase_stats<<<B*H, S, 0, stream>>>(cr, pbuf, magbuf, mc, ms);
    phase_mix<<<BS*H/256, blk, 0, stream>>>(pbuf, magbuf, phase_shifts, mc, ms, nc);
    gemm_bias_act<0><<<g88, blk, 0, stream>>>(nc, 2*H, Wfc, H, bfc, concat + 2*H, 3*H, 2*H);

    // combine + residual + LN
    gemm_bias_act<0><<<g88, blk, 0, stream>>>(concat, 3*H, Wproj, H, bproj, combined, H, 3*H);
    final_ln<<<BS, blk, 0, stream>>>(x, combined, ln_g, ln_b, out);
}

// Round 2
// 162.891 us; speedup vs baseline: 4.5070x; 4.5070x over previous
//
#include <hip/hip_runtime.h>
#include <math.h>

#define H 512
#define B 2
#define S 256
#define BS 512
#define PI_F 3.14159265358979323846f
#define INV_SQRT_D 0.08838834764831845f  // 1/sqrt(128)

typedef __attribute__((ext_vector_type(8))) short short8;
typedef __attribute__((ext_vector_type(4))) float f32x4;

__device__ __forceinline__ unsigned short f2bf(float f) {
    unsigned u = __float_as_uint(f);
    u += 0x7FFFu + ((u >> 16) & 1u);      // round-to-nearest-even
    return (unsigned short)(u >> 16);
}

__device__ __forceinline__ void softmax3(const float* sw, float& w0, float& w1, float& w2)
{
    float s0 = sw[0], s1 = sw[1], s2 = sw[2];
    float mx = fmaxf(s0, fmaxf(s1, s2));
    float e0 = __expf(s0 - mx), e1 = __expf(s1 - mx), e2 = __expf(s2 - mx);
    float inv = 1.f / (e0 + e1 + e2);
    w0 = e0 * inv; w1 = e1 * inv; w2 = e2 * inv;
}

__device__ __forceinline__ void gload16(const unsigned short* g, void* l) {
    __builtin_amdgcn_global_load_lds(
        (const __attribute__((address_space(1))) unsigned int*)g,
        (__attribute__((address_space(3))) unsigned int*)l,
        16, 0, 0);
}

// ------------------------------------------------------------------
// bf16 MFMA GEMM: C[M,N] = epi(A[M,K] @ B[K,N] + bias[N])
// A: [M][K] bf16 row-major (lda=K-stride). Bt: [N][K] bf16 (pre-transposed).
// 64x64 tile, BK=64, 256 threads = 4 waves (2x2), each wave 32x32.
// LDS tiles XOR-swizzled (byte ^= (row&7)<<4), staged via global_load_lds
// with pre-swizzled global source (rule #21: both-sides-or-neither).
// EPI: 0 = bf16 out, bias. 1 = fp32 out, per-col act (qkvt). 2 = fp32 out, bias.
// ------------------------------------------------------------------
template<int EPI>
__global__ __launch_bounds__(256)
void mfma_gemm(const unsigned short* __restrict__ A, int lda,
               const unsigned short* __restrict__ Bt, int ldb,
               const float* __restrict__ bias,
               void* __restrict__ Cout, int ldc, int K)
{
    __shared__ unsigned short As[4096];   // [64 rows][64 k] bf16, swizzled
    __shared__ unsigned short Bs[4096];   // [64 n  ][64 k] bf16, swizzled
    const int tid  = threadIdx.x;
    const int lane = tid & 63, wave = tid >> 6;
    const int wr = wave >> 1, wc = wave & 1;        // 2x2 wave grid
    const int bm = blockIdx.y, bn = blockIdx.x;

    // staging geometry: thread covers LDS bytes d=tid*16 (+4096 for 2nd half)
    const int rowA = tid >> 3;                               // 0..31
    const int sb   = ((tid & 7) << 4) ^ ((rowA & 7) << 4);   // swizzled src byte in row
    const size_t offA0 = (size_t)(bm * 64 + rowA) * lda + (sb >> 1);
    const size_t offA1 = offA0 + (size_t)32 * lda;
    const size_t offB0 = (size_t)(bn * 64 + rowA) * ldb + (sb >> 1);
    const size_t offB1 = offB0 + (size_t)32 * ldb;
    char* AsB = (char*)As;
    char* BsB = (char*)Bs;
    const unsigned ldsOff0 = wave * 1024u;
    const unsigned ldsOff1 = wave * 1024u + 4096u;

    const int fr = lane & 15, grp = lane >> 4;
    // fragment ds_read byte addresses (swizzled); k = kk*32 + grp*8 + j
    int aA[2][2], aB[2][2];
    #pragma unroll
    for (int kk = 0; kk < 2; ++kk) {
        #pragma unroll
        for (int f = 0; f < 2; ++f) {
            int ra = wr * 32 + f * 16 + fr;
            int rb = wc * 32 + f * 16 + fr;
            aA[f][kk] = (ra * 128 + kk * 64 + grp * 16) ^ ((ra & 7) << 4);
            aB[f][kk] = (rb * 128 + kk * 64 + grp * 16) ^ ((rb & 7) << 4);
        }
    }

    f32x4 acc[2][2] = {};

    for (int k0 = 0; k0 < K; k0 += 64) {
        gload16(A  + offA0 + k0, AsB + ldsOff0);
        gload16(A  + offA1 + k0, AsB + ldsOff1);
        gload16(Bt + offB0 + k0, BsB + ldsOff0);
        gload16(Bt + offB1 + k0, BsB + ldsOff1);
        __syncthreads();
        #pragma unroll
        for (int kk = 0; kk < 2; ++kk) {
            short8 a0 = *(const short8*)(AsB + aA[0][kk]);
            short8 a1 = *(const short8*)(AsB + aA[1][kk]);
            short8 b0 = *(const short8*)(BsB + aB[0][kk]);
            short8 b1 = *(const short8*)(BsB + aB[1][kk]);
            acc[0][0] = __builtin_amdgcn_mfma_f32_16x16x32_bf16(a0, b0, acc[0][0], 0, 0, 0);
            acc[0][1] = __builtin_amdgcn_mfma_f32_16x16x32_bf16(a0, b1, acc[0][1], 0, 0, 0);
            acc[1][0] = __builtin_amdgcn_mfma_f32_16x16x32_bf16(a1, b0, acc[1][0], 0, 0, 0);
            acc[1][1] = __builtin_amdgcn_mfma_f32_16x16x32_bf16(a1, b1, acc[1][1], 0, 0, 0);
        }
        __syncthreads();
    }

    // C/D layout (HW-verified): col = lane&15, row = (lane>>4)*4 + reg
    const int erow = bm * 64 + wr * 32 + grp * 4;
    const int ecol = bn * 64 + wc * 32 + fr;
    #pragma unroll
    for (int fm = 0; fm < 2; ++fm)
        #pragma unroll
        for (int fn = 0; fn < 2; ++fn)
            #pragma unroll
            for (int j = 0; j < 4; ++j) {
                int r = erow + fm * 16 + j;
                int c = ecol + fn * 16;
                float v = acc[fm][fn][j] + bias[c];
                if (EPI == 1) {
                    if (c < 512)       v = PI_F / (1.f + __expf(-v));   // omega
                    else if (c < 1024) v = 1.f  / (1.f + __expf(-v));   // amp
                }
                if (EPI == 0) ((unsigned short*)Cout)[(size_t)r * ldc + c] = f2bf(v);
                else          ((float*)Cout)[(size_t)r * ldc + c] = v;
            }
}

// ------------------------------------------------------------------
// prep_all: bf16 converts, weight transposes/concat, combined conv weight,
// im2col of x, concatenated biases. One dispatch, segmented by flat index.
// ------------------------------------------------------------------
__global__ __launch_bounds__(256)
void prep_all(const float* __restrict__ x,
              const float* __restrict__ Wq, const float* __restrict__ Wk,
              const float* __restrict__ Wv, const float* __restrict__ Wtc,
              const float* __restrict__ Wwl, const float* __restrict__ Wo,
              const float* __restrict__ Wfc, const float* __restrict__ Wproj,
              const float* __restrict__ cw1, const float* __restrict__ cw2,
              const float* __restrict__ cw3, const float* __restrict__ scale_w,
              const float* __restrict__ bq, const float* __restrict__ bk,
              const float* __restrict__ bv, const float* __restrict__ btc,
              const float* __restrict__ cb1, const float* __restrict__ cb2,
              const float* __restrict__ cb3,
              unsigned short* __restrict__ xb,
              unsigned short* __restrict__ WcatT,
              unsigned short* __restrict__ WbigT,
              unsigned short* __restrict__ WwlT,
              unsigned short* __restrict__ WoT,
              unsigned short* __restrict__ WfcT,
              unsigned short* __restrict__ WprojT,
              unsigned short* __restrict__ Abig,
              float* __restrict__ bcat1, float* __restrict__ beff)
{
    int idx = blockIdx.x * 256 + threadIdx.x;
    // S0: xb = bf16(x)
    if (idx < 262144) { xb[idx] = f2bf(x[idx]); return; }
    idx -= 262144;
    // S1: WcatT [2560 n][512 k] = [Wq|Wk|Wv|Wtc]^T
    if (idx < 1310720) {
        int n = idx >> 9, k = idx & 511;
        float v;
        if (n < 512)       v = Wq[(k << 9) + n];
        else if (n < 1024) v = Wk[(k << 9) + (n - 512)];
        else if (n < 1536) v = Wv[(k << 9) + (n - 1024)];
        else               v = Wtc[(k << 10) + (n - 1536)];
        WcatT[idx] = f2bf(v);
        return;
    }
    idx -= 1310720;
    // S2: WbigT [512 o][4608 (t*512+i)] — softmax(scale_w)-combined 9-tap conv weight
    if (idx < 2359296) {
        int o = idx / 4608, col = idx - o * 4608;
        int t = col >> 9, i = col & 511;
        float w0, w1, w2; softmax3(scale_w, w0, w1, w2);
        size_t oi = (size_t)o * 512 + i;
        float v = w2 * cw3[oi * 9 + t];
        if (t >= 3 && t < 6) v = fmaf(w0, cw1[oi * 3 + (t - 3)], v);
        if (t >= 2 && t < 7) v = fmaf(w1, cw2[oi * 5 + (t - 2)], v);
        WbigT[idx] = f2bf(v);
        return;
    }
    idx -= 2359296;
    // S3/S4: WwlT / WoT [512][512] transposed
    if (idx < 262144) { int n = idx >> 9, k = idx & 511; WwlT[idx] = f2bf(Wwl[(k << 9) + n]); return; }
    idx -= 262144;
    if (idx < 262144) { int n = idx >> 9, k = idx & 511; WoT[idx] = f2bf(Wo[(k << 9) + n]); return; }
    idx -= 262144;
    // S5: WfcT [512 n][1024 k]
    if (idx < 524288) { int n = idx >> 10, k = idx & 1023; WfcT[idx] = f2bf(Wfc[(k << 9) + n]); return; }
    idx -= 524288;
    // S6: WprojT [512 n][1536 k]
    if (idx < 786432) { int n = idx / 1536, k = idx - n * 1536; WprojT[idx] = f2bf(Wproj[(k << 9) + n]); return; }
    idx -= 786432;
    // S7: Abig [512 r][4608 (t*512+i)] im2col, zero-padded
    if (idx < 2359296) {
        int r = idx / 4608, col = idx - r * 4608;
        int t = col >> 9, i = col & 511;
        int b = r >> 8, s = r & 255;
        int s2 = s + t - 4;
        float v = (s2 >= 0 && s2 < 256) ? x[((size_t)(b * 256 + s2) << 9) + i] : 0.f;
        Abig[idx] = f2bf(v);
        return;
    }
    idx -= 2359296;
    // S8: bcat1[2560]
    if (idx < 2560) {
        float v;
        if (idx < 512)       v = bq[idx];
        else if (idx < 1024) v = bk[idx - 512];
        else if (idx < 1536) v = bv[idx - 1024];
        else                 v = btc[idx - 1536];
        bcat1[idx] = v;
        return;
    }
    idx -= 2560;
    // S9: beff[512]
    if (idx < 512) {
        float w0, w1, w2; softmax3(scale_w, w0, w1, w2);
        beff[idx] = w0 * cb1[idx] + w1 * cb2[idx] + w2 * cb3[idx];
    }
}

// ------------------------------------------------------------------
// Wave attention: amp/omega/ph depend only on query index; |score|<=1/sqrt(D)
// so no max-subtraction needed. One thread per (b,i,c).
// qkvt layout: [512 rows][2560]: omega | amp | v | cr(1024)
// ------------------------------------------------------------------
__global__ __launch_bounds__(512)
void attn_kernel(const float* __restrict__ qkvt, unsigned short* __restrict__ ctx_b)
{
    const int bi = blockIdx.x;          // b*S + i
    const int b = bi >> 8, i = bi & 255;
    const int c = threadIdx.x;          // 0..511
    const float* qrow = qkvt + (size_t)bi * 2560;
    const float om = qrow[c];
    const float am = qrow[512 + c] * INV_SQRT_D;
    const float ph = tanhf(qrow[1024 + c]) * PI_F;
    const float* vb = qkvt + (size_t)(b * 256) * 2560 + 1024 + c;
    float se = 0.f, sev = 0.f;
    for (int j = 0; j < 256; ++j) {
        float ang = fmaf(om, (float)(i - j), ph);
        float e = __expf(am * __cosf(ang));
        se += e;
        sev = fmaf(e, vb[(size_t)j * 2560], sev);
    }
    ctx_b[(size_t)bi * 512 + c] = f2bf(sev / se);
}

// ------------------------------------------------------------------
// Fused phase branch: p/mag + per-(b,c) circular means over S + mix + rebuild.
// Block = (b,c), threads = s (256 == S).
// ------------------------------------------------------------------
__global__ __launch_bounds__(256)
void phase_kernel(const float* __restrict__ qkvt, const float* __restrict__ phase_shifts,
                  unsigned short* __restrict__ nc_b)
{
    const int bc = blockIdx.x;          // b*H + c
    const int b = bc >> 9, c = bc & 511;
    const int s = threadIdx.x;
    const float* row = qkvt + (size_t)(b * 256 + s) * 2560 + 1536;
    float re = row[c], im = row[c + 512];
    float p = atan2f(im, re);
    float mag = sqrtf(fmaf(re, re, fmaf(im, im, 1e-5f)));
    float sp, cp; sincosf(p, &sp, &cp);
    __shared__ float sc[256], ss[256];
    sc[s] = cp; ss[s] = sp;
    __syncthreads();
    for (int off = 128; off > 0; off >>= 1) {
        if (s < off) { sc[s] += sc[s + off]; ss[s] += ss[s + off]; }
        __syncthreads();
    }
    float mcv = sc[0] * (1.f / 256.f), msv = ss[0] * (1.f / 256.f);
    float psh = phase_shifts[c];
    float s2, c2; sincosf(p + psh, &s2, &c2);
    float mixed = c2 * mcv + s2 * msv;
    float np_ = fmaf(0.1f, mixed, p);
    float sn, cn; sincosf(np_, &sn, &cn);
    size_t o = (size_t)(b * 256 + s) * 1024 + c;
    nc_b[o]       = f2bf(mag * cn);
    nc_b[o + 512] = f2bf(mag * sn);
}

// ------------------------------------------------------------------
// Residual + LayerNorm -> d_out (fp32)
// ------------------------------------------------------------------
__global__ __launch_bounds__(256)
void final_ln(const float* __restrict__ x, const float* __restrict__ comb,
              const float* __restrict__ g, const float* __restrict__ bta,
              float* __restrict__ out)
{
    int r = blockIdx.x;
    int t = threadIdx.x;
    const float* xr = x + (size_t)r * H;
    const float* cb = comb + (size_t)r * H;
    float v0 = xr[t] + cb[t];
    float v1 = xr[t + 256] + cb[t + 256];
    __shared__ float red[256];
    red[t] = v0 + v1;
    __syncthreads();
    for (int off = 128; off > 0; off >>= 1) {
        if (t < off) red[t] += red[t + off];
        __syncthreads();
    }
    float mu = red[0] * (1.f / H);
    __syncthreads();
    float d0 = v0 - mu, d1 = v1 - mu;
    red[t] = d0 * d0 + d1 * d1;
    __syncthreads();
    for (int off = 128; off > 0; off >>= 1) {
        if (t < off) red[t] += red[t + off];
        __syncthreads();
    }
    float inv = rsqrtf(red[0] * (1.f / H) + 1e-5f);
    out[(size_t)r * H + t]       = d0 * inv * g[t]       + bta[t];
    out[(size_t)r * H + t + 256] = d1 * inv * g[t + 256] + bta[t + 256];
}

// ------------------------------------------------------------------
extern "C" void kernel_launch(void* const* d_in, const int* in_sizes, int n_in,
                              void* d_out, int out_size, void* d_ws, size_t ws_size,
                              hipStream_t stream)
{
    const float* x   = (const float*)d_in[0];
    const float* Wq  = (const float*)d_in[1];
    const float* bq  = (const float*)d_in[2];
    const float* Wk  = (const float*)d_in[3];
    const float* bk  = (const float*)d_in[4];
    const float* Wv  = (const float*)d_in[5];
    const float* bv  = (const float*)d_in[6];
    const float* Wo  = (const float*)d_in[7];
    const float* bo  = (const float*)d_in[8];
    const float* cw1 = (const float*)d_in[9];
    const float* cb1 = (const float*)d_in[10];
    const float* cw2 = (const float*)d_in[11];
    const float* cb2 = (const float*)d_in[12];
    const float* cw3 = (const float*)d_in[13];
    const float* cb3 = (const float*)d_in[14];
    const float* scale_w = (const float*)d_in[15];
    const float* Wwl = (const float*)d_in[16];
    const float* bwl = (const float*)d_in[17];
    const float* Wtc = (const float*)d_in[18];
    const float* btc = (const float*)d_in[19];
    const float* Wfc = (const float*)d_in[20];
    const float* bfc = (const float*)d_in[21];
    const float* phase_shifts = (const float*)d_in[22];
    const float* Wproj = (const float*)d_in[23];
    const float* bproj = (const float*)d_in[24];
    const float* ln_g = (const float*)d_in[25];
    const float* ln_b = (const float*)d_in[26];
    float* out = (float*)d_out;

    // ---- workspace layout ----
    float* wsf      = (float*)d_ws;
    float* qkvt     = wsf;                      // 512*2560       = 1,310,720 f
    float* combined = qkvt + 1310720;           // 262,144 f
    float* bcat1    = combined + 262144;        // 2,560 f
    float* beff     = bcat1 + 2560;             // 512 f
    unsigned short* wsb = (unsigned short*)(beff + 512);
    unsigned short* xb      = wsb;              // 262,144
    unsigned short* WcatT   = xb      + 262144; // 1,310,720
    unsigned short* WbigT   = WcatT   + 1310720;// 2,359,296
    unsigned short* WwlT    = WbigT   + 2359296;// 262,144
    unsigned short* WoT     = WwlT    + 262144; // 262,144
    unsigned short* WfcT    = WoT     + 262144; // 524,288
    unsigned short* WprojT  = WfcT    + 524288; // 786,432
    unsigned short* Abig    = WprojT  + 786432; // 2,359,296
    unsigned short* convout = Abig    + 2359296;// 262,144
    unsigned short* ctx_b   = convout + 262144; // 262,144
    unsigned short* nc_b    = ctx_b   + 262144; // 524,288
    unsigned short* concat  = nc_b    + 524288; // 786,432 ([512][1536])

    // ---- prep (bf16 conversion / transposes / im2col / combined conv wt) ----
    prep_all<<<31756, 256, 0, stream>>>(x, Wq, Wk, Wv, Wtc, Wwl, Wo, Wfc, Wproj,
                                        cw1, cw2, cw3, scale_w,
                                        bq, bk, bv, btc, cb1, cb2, cb3,
                                        xb, WcatT, WbigT, WwlT, WoT, WfcT, WprojT,
                                        Abig, bcat1, beff);

    // ---- fused QKV + Wtc projection: [512]x[512]->[512][2560] ----
    mfma_gemm<1><<<dim3(40, 8), 256, 0, stream>>>(xb, 512, WcatT, 512, bcat1, qkvt, 2560, 512);

    // ---- wave attention -> ctx (bf16) ----
    attn_kernel<<<512, 512, 0, stream>>>(qkvt, ctx_b);

    // ---- phase branch -> nc (bf16) ----
    phase_kernel<<<1024, 256, 0, stream>>>(qkvt, phase_shifts, nc_b);

    // ---- wavelet: 9-tap conv as GEMM (K=4608), then @Wwl ----
    mfma_gemm<0><<<dim3(8, 8), 256, 0, stream>>>(Abig, 4608, WbigT, 4608, beff, convout, 512, 4608);
    mfma_gemm<0><<<dim3(8, 8), 256, 0, stream>>>(convout, 512, WwlT, 512, bwl, concat + 512, 1536, 512);

    // ---- wave out / phase out into concat ----
    mfma_gemm<0><<<dim3(8, 8), 256, 0, stream>>>(ctx_b, 512, WoT, 512, bo, concat, 1536, 512);
    mfma_gemm<0><<<dim3(8, 8), 256, 0, stream>>>(nc_b, 1024, WfcT, 1024, bfc, concat + 1024, 1536, 1024);

    // ---- combined projection + residual + LN ----
    mfma_gemm<2><<<dim3(8, 8), 256, 0, stream>>>(concat, 1536, WprojT, 1536, bproj, combined, 512, 1536);
    final_ln<<<512, 256, 0, stream>>>(x, combined, ln_g, ln_b, out);
}

// Round 3
// 102.653 us; speedup vs baseline: 7.1517x; 1.5868x over previous
//
#include <hip/hip_runtime.h>
#include <math.h>

#define H 512
#define B 2
#define S 256
#define BS 512
#define PI_F 3.14159265358979323846f
#define INV_SQRT_D 0.08838834764831845f  // 1/sqrt(128)

typedef __attribute__((ext_vector_type(8))) short short8;
typedef __attribute__((ext_vector_type(4))) float f32x4;

__device__ __forceinline__ unsigned short f2bf(float f) {
    unsigned u = __float_as_uint(f);
    u += 0x7FFFu + ((u >> 16) & 1u);      // round-to-nearest-even
    return (unsigned short)(u >> 16);
}

__device__ __forceinline__ void softmax3(const float* sw, float& w0, float& w1, float& w2)
{
    float s0 = sw[0], s1 = sw[1], s2 = sw[2];
    float mx = fmaxf(s0, fmaxf(s1, s2));
    float e0 = __expf(s0 - mx), e1 = __expf(s1 - mx), e2 = __expf(s2 - mx);
    float inv = 1.f / (e0 + e1 + e2);
    w0 = e0 * inv; w1 = e1 * inv; w2 = e2 * inv;
}

__device__ __forceinline__ void gload16(const unsigned short* g, void* l) {
    __builtin_amdgcn_global_load_lds(
        (const __attribute__((address_space(1))) unsigned int*)g,
        (__attribute__((address_space(3))) unsigned int*)l,
        16, 0, 0);
}

// ------------------------------------------------------------------
// Shared MFMA GEMM body: C = epi(A[M,K] @ Bt[N,K]^T + bias), 64x64 tile,
// BK=64, 4 waves (2x2), double-buffered LDS with 2-phase prefetch:
// next tile's global_load_lds issued BEFORE current tile's MFMA;
// __syncthreads() (vmcnt+lgkm drain) once per K-step.
// EPI: 0 = bf16 out + bias. 1 = fp32 out + qkvt col-activation + bias.
// 3 = fp32 partial out, no bias (split-K).
// ------------------------------------------------------------------
template<int EPI>
__device__ __forceinline__ void gemm_body(
    const unsigned short* __restrict__ A, int lda,
    const unsigned short* __restrict__ Bt, int ldb,
    const float* __restrict__ bias,
    void* __restrict__ Cout, int ldc, int ccol0,
    int row0, int col0, int kstart, int kend,
    unsigned short (*As)[4096], unsigned short (*Bs)[4096])
{
    const int tid = threadIdx.x;
    const int lane = tid & 63, wave = tid >> 6;
    const int wr = wave >> 1, wc = wave & 1;
    const int rowA = tid >> 3;                               // 0..31
    const int sb = ((tid & 7) << 4) ^ ((rowA & 7) << 4);     // swizzled byte-in-row
    const size_t offA0 = (size_t)(row0 + rowA) * lda + (sb >> 1);
    const size_t offA1 = offA0 + (size_t)32 * lda;
    const size_t offB0 = (size_t)(col0 + rowA) * ldb + (sb >> 1);
    const size_t offB1 = offB0 + (size_t)32 * ldb;
    const unsigned ldsO0 = wave * 1024u, ldsO1 = ldsO0 + 4096u;

    const int fr = lane & 15, grp = lane >> 4;
    int aA[2][2], aB[2][2];
    #pragma unroll
    for (int kk = 0; kk < 2; ++kk)
        #pragma unroll
        for (int f = 0; f < 2; ++f) {
            int ra = wr * 32 + f * 16 + fr;
            int rb = wc * 32 + f * 16 + fr;
            aA[f][kk] = (ra * 128 + kk * 64 + grp * 16) ^ ((ra & 7) << 4);
            aB[f][kk] = (rb * 128 + kk * 64 + grp * 16) ^ ((rb & 7) << 4);
        }

    const int nt = (kend - kstart) >> 6;
    auto stage = [&](int buf, int k0) {
        char* ab = (char*)As[buf]; char* bb = (char*)Bs[buf];
        gload16(A  + offA0 + k0, ab + ldsO0);
        gload16(A  + offA1 + k0, ab + ldsO1);
        gload16(Bt + offB0 + k0, bb + ldsO0);
        gload16(Bt + offB1 + k0, bb + ldsO1);
    };

    stage(0, kstart);
    __syncthreads();
    f32x4 acc[2][2] = {};
    int cur = 0;
    for (int t = 0; t < nt; ++t) {
        if (t + 1 < nt) stage(cur ^ 1, kstart + (t + 1) * 64);   // prefetch next
        const char* AsB = (const char*)As[cur];
        const char* BsB = (const char*)Bs[cur];
        #pragma unroll
        for (int kk = 0; kk < 2; ++kk) {
            short8 a0 = *(const short8*)(AsB + aA[0][kk]);
            short8 a1 = *(const short8*)(AsB + aA[1][kk]);
            short8 b0 = *(const short8*)(BsB + aB[0][kk]);
            short8 b1 = *(const short8*)(BsB + aB[1][kk]);
            acc[0][0] = __builtin_amdgcn_mfma_f32_16x16x32_bf16(a0, b0, acc[0][0], 0, 0, 0);
            acc[0][1] = __builtin_amdgcn_mfma_f32_16x16x32_bf16(a0, b1, acc[0][1], 0, 0, 0);
            acc[1][0] = __builtin_amdgcn_mfma_f32_16x16x32_bf16(a1, b0, acc[1][0], 0, 0, 0);
            acc[1][1] = __builtin_amdgcn_mfma_f32_16x16x32_bf16(a1, b1, acc[1][1], 0, 0, 0);
        }
        __syncthreads();   // drains vmcnt (next buf staged) + lgkm (reads done)
        cur ^= 1;
    }

    const int erow = row0 + wr * 32 + grp * 4;
    const int ecol = col0 + wc * 32 + fr;
    #pragma unroll
    for (int fm = 0; fm < 2; ++fm)
        #pragma unroll
        for (int fn = 0; fn < 2; ++fn)
            #pragma unroll
            for (int j = 0; j < 4; ++j) {
                int r = erow + fm * 16 + j;
                int c = ecol + fn * 16;
                float v = acc[fm][fn][j];
                if (EPI != 3) v += bias[c];
                if (EPI == 1) {
                    if (c < 512)       v = PI_F / (1.f + __expf(-v));
                    else if (c < 1024) v = 1.f  / (1.f + __expf(-v));
                }
                if (EPI == 0) ((unsigned short*)Cout)[(size_t)r * ldc + ccol0 + c] = f2bf(v);
                else          ((float*)Cout)[(size_t)r * ldc + ccol0 + c] = v;
            }
}

__global__ __launch_bounds__(256)
void gemm_qkvt(const unsigned short* __restrict__ xb, const unsigned short* __restrict__ WcatT,
               const float* __restrict__ bcat1, float* __restrict__ qkvt)
{
    __shared__ unsigned short As[2][4096], Bs[2][4096];
    gemm_body<1>(xb, 512, WcatT, 512, bcat1, qkvt, 2560, 0,
                 blockIdx.y * 64, blockIdx.x * 64, 0, 512, As, Bs);
}

__global__ __launch_bounds__(256)
void gemm_b3(const unsigned short* __restrict__ ctx_b, const unsigned short* __restrict__ WoT, const float* __restrict__ bo,
             const unsigned short* __restrict__ convout, const unsigned short* __restrict__ WwlT, const float* __restrict__ bwl,
             const unsigned short* __restrict__ nc_b, const unsigned short* __restrict__ WfcT, const float* __restrict__ bfc,
             unsigned short* __restrict__ concat)
{
    __shared__ unsigned short As[2][4096], Bs[2][4096];
    const unsigned short *A, *Bt; const float* bias; int lda, K, ccol0;
    if (blockIdx.z == 0)      { A = ctx_b;   Bt = WoT;  bias = bo;  lda = 512;  K = 512;  ccol0 = 0; }
    else if (blockIdx.z == 1) { A = convout; Bt = WwlT; bias = bwl; lda = 512;  K = 512;  ccol0 = 512; }
    else                      { A = nc_b;    Bt = WfcT; bias = bfc; lda = 1024; K = 1024; ccol0 = 1024; }
    gemm_body<0>(A, lda, Bt, lda, bias, concat, 1536, ccol0,
                 blockIdx.y * 64, blockIdx.x * 64, 0, K, As, Bs);
}

__global__ __launch_bounds__(256)
void gemm_projk(const unsigned short* __restrict__ concat, const unsigned short* __restrict__ WprojT,
                float* __restrict__ projP)
{
    __shared__ unsigned short As[2][4096], Bs[2][4096];
    int z = blockIdx.z;
    gemm_body<3>(concat, 1536, WprojT, 1536, nullptr, projP + (size_t)z * 262144, 512, 0,
                 blockIdx.y * 64, blockIdx.x * 64, z * 384, (z + 1) * 384, As, Bs);
}

// ------------------------------------------------------------------
// Conv-as-GEMM, split-K=4, A read directly from zero-padded xpad[B][264][512]
// (row = s + tap; k = tap*512 + i). No im2col buffer. fp32 partials.
// ------------------------------------------------------------------
__global__ __launch_bounds__(256)
void conv_gemm(const unsigned short* __restrict__ xpad,
               const unsigned short* __restrict__ WbigT,
               float* __restrict__ convP)
{
    __shared__ unsigned short As[2][4096], Bs[2][4096];
    const int tid = threadIdx.x;
    const int lane = tid & 63, wave = tid >> 6;
    const int wr = wave >> 1, wc = wave & 1;
    const int bm = blockIdx.y, bn = blockIdx.x, z = blockIdx.z;
    const int rowA = tid >> 3;
    const int sb = ((tid & 7) << 4) ^ ((rowA & 7) << 4);
    const int sbk = sb >> 1;
    const int r0 = bm * 64 + rowA;
    const int base0 = ((r0 >> 8) * 264 + (r0 & 255)) * 512;
    const int r1 = r0 + 32;
    const int base1 = ((r1 >> 8) * 264 + (r1 & 255)) * 512;
    const size_t offB0 = (size_t)(bn * 64 + rowA) * 4608 + sbk;
    const size_t offB1 = offB0 + (size_t)32 * 4608;
    const unsigned ldsO0 = wave * 1024u, ldsO1 = ldsO0 + 4096u;
    const int kstart = z * 1152;

    const int fr = lane & 15, grp = lane >> 4;
    int aA[2][2], aB[2][2];
    #pragma unroll
    for (int kk = 0; kk < 2; ++kk)
        #pragma unroll
        for (int f = 0; f < 2; ++f) {
            int ra = wr * 32 + f * 16 + fr;
            int rb = wc * 32 + f * 16 + fr;
            aA[f][kk] = (ra * 128 + kk * 64 + grp * 16) ^ ((ra & 7) << 4);
            aB[f][kk] = (rb * 128 + kk * 64 + grp * 16) ^ ((rb & 7) << 4);
        }

    auto stage = [&](int buf, int k0) {
        int tap = k0 >> 9;
        int ro = tap * 512 + (k0 & 511) + sbk;   // row shift + in-row k (swizzled)
        char* ab = (char*)As[buf]; char* bb = (char*)Bs[buf];
        gload16(xpad + base0 + ro, ab + ldsO0);
        gload16(xpad + base1 + ro, ab + ldsO1);
        gload16(WbigT + offB0 + k0, bb + ldsO0);
        gload16(WbigT + offB1 + k0, bb + ldsO1);
    };

    stage(0, kstart);
    __syncthreads();
    f32x4 acc[2][2] = {};
    int cur = 0;
    for (int t = 0; t < 18; ++t) {
        if (t < 17) stage(cur ^ 1, kstart + (t + 1) * 64);
        const char* AsB = (const char*)As[cur];
        const char* BsB = (const char*)Bs[cur];
        #pragma unroll
        for (int kk = 0; kk < 2; ++kk) {
            short8 a0 = *(const short8*)(AsB + aA[0][kk]);
            short8 a1 = *(const short8*)(AsB + aA[1][kk]);
            short8 b0 = *(const short8*)(BsB + aB[0][kk]);
            short8 b1 = *(const short8*)(BsB + aB[1][kk]);
            acc[0][0] = __builtin_amdgcn_mfma_f32_16x16x32_bf16(a0, b0, acc[0][0], 0, 0, 0);
            acc[0][1] = __builtin_amdgcn_mfma_f32_16x16x32_bf16(a0, b1, acc[0][1], 0, 0, 0);
            acc[1][0] = __builtin_amdgcn_mfma_f32_16x16x32_bf16(a1, b0, acc[1][0], 0, 0, 0);
            acc[1][1] = __builtin_amdgcn_mfma_f32_16x16x32_bf16(a1, b1, acc[1][1], 0, 0, 0);
        }
        __syncthreads();
        cur ^= 1;
    }

    float* Cp = convP + (size_t)z * 262144;
    const int erow = bm * 64 + wr * 32 + grp * 4;
    const int ecol = bn * 64 + wc * 32 + fr;
    #pragma unroll
    for (int fm = 0; fm < 2; ++fm)
        #pragma unroll
        for (int fn = 0; fn < 2; ++fn)
            #pragma unroll
            for (int j = 0; j < 4; ++j)
                Cp[(size_t)(erow + fm * 16 + j) * 512 + ecol + fn * 16] = acc[fm][fn][j];
}

__global__ __launch_bounds__(256)
void reduce_conv(const float* __restrict__ convP, const float* __restrict__ beff,
                 unsigned short* __restrict__ convout)
{
    int idx = blockIdx.x * 256 + threadIdx.x;
    int c = idx & 511;
    float v = beff[c] + convP[idx] + convP[idx + 262144] + convP[idx + 524288] + convP[idx + 786432];
    convout[idx] = f2bf(v);
}

// ------------------------------------------------------------------
// prep_misc: xb (bf16 x), xpad (zero-padded bf16 x), WbigT (combined conv
// weight), concatenated biases. Flat-index segmented.
// ------------------------------------------------------------------
__global__ __launch_bounds__(256)
void prep_misc(const float* __restrict__ x,
               const float* __restrict__ cw1, const float* __restrict__ cw2,
               const float* __restrict__ cw3, const float* __restrict__ scale_w,
               const float* __restrict__ bq, const float* __restrict__ bk,
               const float* __restrict__ bv, const float* __restrict__ btc,
               const float* __restrict__ cb1, const float* __restrict__ cb2,
               const float* __restrict__ cb3,
               unsigned short* __restrict__ xb, unsigned short* __restrict__ xpad,
               unsigned short* __restrict__ WbigT,
               float* __restrict__ bcat1, float* __restrict__ beff)
{
    int idx = blockIdx.x * 256 + threadIdx.x;
    if (idx < 262144) { xb[idx] = f2bf(x[idx]); return; }
    idx -= 262144;
    if (idx < 270336) {                        // xpad[B][264][512], 4 zero rows each side
        int b = idx / 135168, rem = idx - b * 135168;
        int srow = rem >> 9, i = rem & 511;
        int s2 = srow - 4;
        xpad[idx] = (s2 >= 0 && s2 < 256) ? f2bf(x[((size_t)(b * 256 + s2) << 9) + i])
                                          : (unsigned short)0;
        return;
    }
    idx -= 270336;
    if (idx < 2359296) {                       // WbigT [512 o][4608 = t*512+i]
        int o = idx / 4608, col = idx - o * 4608;
        int t = col >> 9, i = col & 511;
        float w0, w1, w2; softmax3(scale_w, w0, w1, w2);
        size_t oi = (size_t)o * 512 + i;
        float v = w2 * cw3[oi * 9 + t];
        if (t >= 3 && t < 6) v = fmaf(w0, cw1[oi * 3 + (t - 3)], v);
        if (t >= 2 && t < 7) v = fmaf(w1, cw2[oi * 5 + (t - 2)], v);
        WbigT[idx] = f2bf(v);
        return;
    }
    idx -= 2359296;
    if (idx < 2560) {
        float v;
        if (idx < 512)       v = bq[idx];
        else if (idx < 1024) v = bk[idx - 512];
        else if (idx < 1536) v = bv[idx - 1024];
        else                 v = btc[idx - 1536];
        bcat1[idx] = v;
        return;
    }
    idx -= 2560;
    if (idx < 512) {
        float w0, w1, w2; softmax3(scale_w, w0, w1, w2);
        beff[idx] = w0 * cb1[idx] + w1 * cb2[idx] + w2 * cb3[idx];
    }
}

// ------------------------------------------------------------------
// LDS-tiled fp32->bf16 weight transposes (coalesced both sides).
// ------------------------------------------------------------------
__global__ __launch_bounds__(256)
void transpose_weights(const float* __restrict__ Wq, const float* __restrict__ Wk,
                       const float* __restrict__ Wv, const float* __restrict__ Wtc,
                       const float* __restrict__ Wo, const float* __restrict__ Wwl,
                       const float* __restrict__ Wfc, const float* __restrict__ Wproj,
                       unsigned short* __restrict__ WcatT, unsigned short* __restrict__ WoT,
                       unsigned short* __restrict__ WwlT, unsigned short* __restrict__ WfcT,
                       unsigned short* __restrict__ WprojT)
{
    __shared__ float tile[32][33];
    int t = blockIdx.x;
    const float* src; unsigned short* dst;
    int srcld, dstld, ntk, drow0;
    if (t < 256)       {           src = Wq;    srcld = 512;  dst = WcatT;  dstld = 512;  ntk = 16; drow0 = 0; }
    else if (t < 512)  { t -= 256; src = Wk;    srcld = 512;  dst = WcatT;  dstld = 512;  ntk = 16; drow0 = 512; }
    else if (t < 768)  { t -= 512; src = Wv;    srcld = 512;  dst = WcatT;  dstld = 512;  ntk = 16; drow0 = 1024; }
    else if (t < 1280) { t -= 768; src = Wtc;   srcld = 1024; dst = WcatT;  dstld = 512;  ntk = 16; drow0 = 1536; }
    else if (t < 1536) { t -= 1280; src = Wo;   srcld = 512;  dst = WoT;    dstld = 512;  ntk = 16; drow0 = 0; }
    else if (t < 1792) { t -= 1536; src = Wwl;  srcld = 512;  dst = WwlT;   dstld = 512;  ntk = 16; drow0 = 0; }
    else if (t < 2304) { t -= 1792; src = Wfc;  srcld = 512;  dst = WfcT;   dstld = 1024; ntk = 32; drow0 = 0; }
    else               { t -= 2304; src = Wproj; srcld = 512; dst = WprojT; dstld = 1536; ntk = 48; drow0 = 0; }
    int tk = t % ntk, tn = t / ntk;
    int r8 = threadIdx.x >> 5, c = threadIdx.x & 31;
    #pragma unroll
    for (int rr = 0; rr < 4; ++rr) {
        int r = r8 + rr * 8;
        tile[r][c] = src[(size_t)(tk * 32 + r) * srcld + tn * 32 + c];
    }
    __syncthreads();
    #pragma unroll
    for (int rr = 0; rr < 4; ++rr) {
        int r = r8 + rr * 8;
        dst[(size_t)(drow0 + tn * 32 + r) * dstld + tk * 32 + c] = f2bf(tile[c][r]);
    }
}

// ------------------------------------------------------------------
// Wave attention (query-only score params; no max-subtraction needed).
// ------------------------------------------------------------------
__global__ __launch_bounds__(512)
void attn_kernel(const float* __restrict__ qkvt, unsigned short* __restrict__ ctx_b)
{
    const int bi = blockIdx.x;
    const int b = bi >> 8, i = bi & 255;
    const int c = threadIdx.x;
    const float* qrow = qkvt + (size_t)bi * 2560;
    const float om = qrow[c];
    const float am = qrow[512 + c] * INV_SQRT_D;
    const float ph = tanhf(qrow[1024 + c]) * PI_F;
    const float* vb = qkvt + (size_t)(b * 256) * 2560 + 1024 + c;
    float se = 0.f, sev = 0.f;
    for (int j = 0; j < 256; ++j) {
        float ang = fmaf(om, (float)(i - j), ph);
        float e = __expf(am * __cosf(ang));
        se += e;
        sev = fmaf(e, vb[(size_t)j * 2560], sev);
    }
    ctx_b[(size_t)bi * 512 + c] = f2bf(sev / se);
}

// ------------------------------------------------------------------
// Fused phase branch (shuffle-based circular-mean reduction).
// ------------------------------------------------------------------
__global__ __launch_bounds__(256)
void phase_kernel(const float* __restrict__ qkvt, const float* __restrict__ phase_shifts,
                  unsigned short* __restrict__ nc_b)
{
    const int bc = blockIdx.x;
    const int b = bc >> 9, c = bc & 511;
    const int s = threadIdx.x;
    const float* row = qkvt + (size_t)(b * 256 + s) * 2560 + 1536;
    float re = row[c], im = row[c + 512];
    float p = atan2f(im, re);
    float mag = sqrtf(fmaf(re, re, fmaf(im, im, 1e-5f)));
    float sp, cp; sincosf(p, &sp, &cp);
    float cs = cp, sn = sp;
    #pragma unroll
    for (int m = 32; m; m >>= 1) { cs += __shfl_xor(cs, m); sn += __shfl_xor(sn, m); }
    __shared__ float wred[8];
    int w = s >> 6, l = s & 63;
    if (l == 0) { wred[w] = cs; wred[4 + w] = sn; }
    __syncthreads();
    float mcv = (wred[0] + wred[1] + wred[2] + wred[3]) * (1.f / 256.f);
    float msv = (wred[4] + wred[5] + wred[6] + wred[7]) * (1.f / 256.f);
    float psh = phase_shifts[c];
    float s2_, c2_; sincosf(p + psh, &s2_, &c2_);
    float mixed = c2_ * mcv + s2_ * msv;
    float np_ = fmaf(0.1f, mixed, p);
    float snn, cnn; sincosf(np_, &snn, &cnn);
    size_t o = (size_t)(b * 256 + s) * 1024 + c;
    nc_b[o]       = f2bf(mag * cnn);
    nc_b[o + 512] = f2bf(mag * snn);
}

// ------------------------------------------------------------------
// Final: sum proj split-K partials + bias + residual + LayerNorm.
// ------------------------------------------------------------------
__global__ __launch_bounds__(256)
void final_ln(const float* __restrict__ x, const float* __restrict__ projP,
              const float* __restrict__ bproj,
              const float* __restrict__ g, const float* __restrict__ bta,
              float* __restrict__ out)
{
    int r = blockIdx.x, t = threadIdx.x;
    size_t o0 = (size_t)r * 512 + t, o1 = o0 + 256;
    float c0 = bproj[t]       + projP[o0] + projP[o0 + 262144] + projP[o0 + 524288] + projP[o0 + 786432];
    float c1 = bproj[t + 256] + projP[o1] + projP[o1 + 262144] + projP[o1 + 524288] + projP[o1 + 786432];
    float v0 = x[o0] + c0, v1 = x[o1] + c1;
    float sum = v0 + v1;
    #pragma unroll
    for (int m = 32; m; m >>= 1) sum += __shfl_xor(sum, m);
    __shared__ float wred[8];
    int w = t >> 6, l = t & 63;
    if (l == 0) wred[w] = sum;
    __syncthreads();
    float mu = (wred[0] + wred[1] + wred[2] + wred[3]) * (1.f / 512.f);
    float d0 = v0 - mu, d1 = v1 - mu;
    float s2 = d0 * d0 + d1 * d1;
    #pragma unroll
    for (int m = 32; m; m >>= 1) s2 += __shfl_xor(s2, m);
    if (l == 0) wred[4 + w] = s2;
    __syncthreads();
    float inv = rsqrtf((wred[4] + wred[5] + wred[6] + wred[7]) * (1.f / 512.f) + 1e-5f);
    out[o0] = d0 * inv * g[t]       + bta[t];
    out[o1] = d1 * inv * g[t + 256] + bta[t + 256];
}

// ------------------------------------------------------------------
extern "C" void kernel_launch(void* const* d_in, const int* in_sizes, int n_in,
                              void* d_out, int out_size, void* d_ws, size_t ws_size,
                              hipStream_t stream)
{
    const float* x   = (const float*)d_in[0];
    const float* Wq  = (const float*)d_in[1];
    const float* bq  = (const float*)d_in[2];
    const float* Wk  = (const float*)d_in[3];
    const float* bk  = (const float*)d_in[4];
    const float* Wv  = (const float*)d_in[5];
    const float* bv  = (const float*)d_in[6];
    const float* Wo  = (const float*)d_in[7];
    const float* bo  = (const float*)d_in[8];
    const float* cw1 = (const float*)d_in[9];
    const float* cb1 = (const float*)d_in[10];
    const float* cw2 = (const float*)d_in[11];
    const float* cb2 = (const float*)d_in[12];
    const float* cw3 = (const float*)d_in[13];
    const float* cb3 = (const float*)d_in[14];
    const float* scale_w = (const float*)d_in[15];
    const float* Wwl = (const float*)d_in[16];
    const float* bwl = (const float*)d_in[17];
    const float* Wtc = (const float*)d_in[18];
    const float* btc = (const float*)d_in[19];
    const float* Wfc = (const float*)d_in[20];
    const float* bfc = (const float*)d_in[21];
    const float* phase_shifts = (const float*)d_in[22];
    const float* Wproj = (const float*)d_in[23];
    const float* bproj = (const float*)d_in[24];
    const float* ln_g = (const float*)d_in[25];
    const float* ln_b = (const float*)d_in[26];
    float* out = (float*)d_out;

    // ---- workspace layout ----
    float* wsf    = (float*)d_ws;
    float* qkvt   = wsf;                        // 1,310,720 f
    float* convP  = qkvt + 1310720;             // 1,048,576 f (4 x 512x512)
    float* projP  = convP + 1048576;            // 1,048,576 f (4 x 512x512)
    float* bcat1  = projP + 1048576;            // 2,560 f
    float* beff   = bcat1 + 2560;               // 512 f
    unsigned short* u = (unsigned short*)(beff + 512);
    unsigned short* xb      = u;                // 262,144
    unsigned short* xpad    = xb + 262144;      // 270,336
    unsigned short* WcatT   = xpad + 270336;    // 1,310,720
    unsigned short* WbigT   = WcatT + 1310720;  // 2,359,296
    unsigned short* WoT     = WbigT + 2359296;  // 262,144
    unsigned short* WwlT    = WoT + 262144;     // 262,144
    unsigned short* WfcT    = WwlT + 262144;    // 524,288
    unsigned short* WprojT  = WfcT + 524288;    // 786,432
    unsigned short* convout = WprojT + 786432;  // 262,144
    unsigned short* ctx_b   = convout + 262144; // 262,144
    unsigned short* nc_b    = ctx_b + 262144;   // 524,288
    unsigned short* concat  = nc_b + 524288;    // 786,432

    prep_misc<<<11308, 256, 0, stream>>>(x, cw1, cw2, cw3, scale_w,
                                         bq, bk, bv, btc, cb1, cb2, cb3,
                                         xb, xpad, WbigT, bcat1, beff);
    transpose_weights<<<3072, 256, 0, stream>>>(Wq, Wk, Wv, Wtc, Wo, Wwl, Wfc, Wproj,
                                                WcatT, WoT, WwlT, WfcT, WprojT);

    // conv split-K partials (needs only prep_misc outputs)
    conv_gemm<<<dim3(8, 8, 4), 256, 0, stream>>>(xpad, WbigT, convP);

    // fused QKV + Wtc projection
    gemm_qkvt<<<dim3(40, 8), 256, 0, stream>>>(xb, WcatT, bcat1, qkvt);

    attn_kernel<<<512, 512, 0, stream>>>(qkvt, ctx_b);
    phase_kernel<<<1024, 256, 0, stream>>>(qkvt, phase_shifts, nc_b);
    reduce_conv<<<1024, 256, 0, stream>>>(convP, beff, convout);

    // three branch-output GEMMs in one dispatch
    gemm_b3<<<dim3(8, 8, 3), 256, 0, stream>>>(ctx_b, WoT, bo, convout, WwlT, bwl,
                                               nc_b, WfcT, bfc, concat);

    // Wproj split-K partials
    gemm_projk<<<dim3(8, 8, 4), 256, 0, stream>>>(concat, WprojT, projP);

    // partial-reduce + bias + residual + LN
    final_ln<<<512, 256, 0, stream>>>(x, projP, bproj, ln_g, ln_b, out);
}